// Round 14
// baseline (62.866 us; speedup 1.0000x reference)
//
#include <hip/hip_runtime.h>
#include <math.h>

// LazyEqProp closed form (verified rounds 1-13):
//   E  = x @ We^T + be
//   m0 = mean|E|  > eps ;  H0 = m0 * 0.5*tanh(E  @ W0^T + b0)
//   m1 = mean|H0| > eps ;  H1 = m1 * 0.5*tanh(H0 @ W1^T + b1)
//   m2 = mean|H1| > eps ;  H2 = m2 * 0.5*tanh(H1 @ W2^T + b2)
//   out = H2 @ Wh^T + bh
//
// Round 14: FIVE dispatches — the fp32->f16 convert pre-pass is gone.
//  - gemm-E reg-stages x/We fp32 directly (r3-proven 1-barrier dbuf loop),
//    converting to f16 in-register (RTN casts, bit-identical to old path);
//    112 extra blocks convert W/Wh (r9-proven); dispatch boundary publishes.
//  - all row-sum emits become deterministic per-(m, n-slot) partial stores
//    (part[m*32 + nt*2 + nh], one writer per slot, no zeroing, no atomics);
//    consumers sum 32 contiguous floats per row in the epilogue.
//  - H0/H1/H2 (gemm8w) and head (gemm2b) K-loops byte-identical to r13.

using half_t = _Float16;
typedef _Float16 f16x4 __attribute__((ext_vector_type(4)));
typedef _Float16 f16x8 __attribute__((ext_vector_type(8)));
typedef float    f32x4 __attribute__((ext_vector_type(4)));

constexpr int KDIM = 1024;
constexpr int ROWB = KDIM * 2;  // bytes per swizzled f16 row
constexpr float EPS_GATE = 0.01f;

__device__ __forceinline__ float tanh_fast(float z) {
    return 1.0f - 2.0f / (__expf(2.0f * z) + 1.0f);  // safe at +-inf
}

__device__ __forceinline__ void gload16(const void* g, void* l) {
    __builtin_amdgcn_global_load_lds(
        (const __attribute__((address_space(1))) void*)g,
        (__attribute__((address_space(3))) void*)l, 16, 0, 0);
}

// convert one fp32 row to swizzled f16: row r, byte p <- element (p^((r&7)<<4))/2
__device__ __forceinline__ void conv_row(const float* __restrict__ src,
                                         half_t* __restrict__ dst,
                                         int row, int t) {
    const f32x4 v = *(const f32x4*)(src + (size_t)row * KDIM + 4 * t);
    f16x4 h;
    h[0] = (half_t)v[0]; h[1] = (half_t)v[1]; h[2] = (half_t)v[2]; h[3] = (half_t)v[3];
    const int p = (8 * t) ^ ((row & 7) << 4);
    *(f16x4*)((char*)dst + (size_t)row * ROWB + p) = h;
}

__device__ __forceinline__ f16x8 cvt8(f32x4 a, f32x4 b) {
    f16x8 h;
    h[0] = (half_t)a[0]; h[1] = (half_t)a[1]; h[2] = (half_t)a[2]; h[3] = (half_t)a[3];
    h[4] = (half_t)b[0]; h[5] = (half_t)b[1]; h[6] = (half_t)b[2]; h[7] = (half_t)b[3];
    return h;
}

// read 32-slot partial row sum
__device__ __forceinline__ float part_sum(const float* __restrict__ part, int m) {
    const f32x4* pp = (const f32x4*)(part + (size_t)m * 32);
    f32x4 t = pp[0] + pp[1] + pp[2] + pp[3] + pp[4] + pp[5] + pp[6] + pp[7];
    return t[0] + t[1] + t[2] + t[3];
}

// ---- gemm-E: E = x @ We^T + be, reg-staged from fp32; also converts W/Wh
// (blocks 256..367) and emits |E| row-sum partials. Tile 128m x 64n x 64k,
// 8 waves (4m x 2n), wave tile 32x32; double-buffered LDS, 1 barrier/step.
__global__ __launch_bounds__(512)
void gemmE_rs(const float* __restrict__ x, const float* __restrict__ We,
              const float* __restrict__ be,
              const float* __restrict__ Wf, const float* __restrict__ Whf,
              half_t* __restrict__ W16, half_t* __restrict__ Wh16,
              float* __restrict__ part0, half_t* __restrict__ Eout) {
    __shared__ alignas(16) char smem[2 * 24576];  // 48 KB

    const int tid = threadIdx.x;
    const int bid = blockIdx.x;

    if (bid >= 256) {  // converter blocks: W (3072 rows) + Wh (512), 32 each
        const int bid2 = bid - 256;
        const int t = tid & 255;
        const int rh = tid >> 8;
#pragma unroll
        for (int q = 0; q < 16; ++q) {
            const int r = bid2 * 32 + q * 2 + rh;  // [0, 3584)
            if (r < 3072) conv_row(Wf, W16, r, t);
            else          conv_row(Whf, Wh16, r - 3072, t);
        }
        return;
    }

    // XCD-aware: xcd = bid&7 owns m-tiles {2x,2x+1} across all n-tiles.
    const int m0 = ((bid & 7) * 2 + ((bid >> 3) & 1)) * 128;
    const int n0 = (bid >> 4) * 64;

    // reg-staging (fp32): thread covers granule (srow, g) of P0/P1/Q.
    // LDS granule G*16 must hold elements s*64 + (g*8 ^ (srow&7)*8) .. +8
    // (swizzle local to each 64-element step window).
    const int srow = tid >> 3;                       // 0..63
    const int g    = tid & 7;
    const int e8   = (g * 8) ^ ((srow & 7) * 8);
    const float* gp0 = x  + (size_t)(m0 + srow) * KDIM + e8;        // rows [0,64)
    const float* gp1 = x  + (size_t)(m0 + 64 + srow) * KDIM + e8;   // rows [64,128)
    const float* gq  = We + (size_t)(n0 + srow) * KDIM + e8;        // rows [0,64)
    const int ldsT = tid * 16;

    const int lane = tid & 63;
    const int w = tid >> 6;
    const int wm = (w & 3) * 32;
    const int wn = (w >> 2) * 32;
    const int l15 = lane & 15, l4 = lane >> 4;
    const int off0 = (l4 * 16) ^ ((lane & 7) << 4);
    const int off1 = off0 ^ 64;

    f32x4 rp[6];
    auto load = [&](int s) {
        const int o = s * 64;
        rp[0] = *(const f32x4*)(gp0 + o); rp[1] = *(const f32x4*)(gp0 + o + 4);
        rp[2] = *(const f32x4*)(gp1 + o); rp[3] = *(const f32x4*)(gp1 + o + 4);
        rp[4] = *(const f32x4*)(gq  + o); rp[5] = *(const f32x4*)(gq  + o + 4);
    };

    f32x4 acc[2][2] = {};  // [n-frag][m-frag]

    load(0);
    for (int s = 0; s < 16; ++s) {
        char* buf = smem + (s & 1) * 24576;
        // write tile s (rp valid: compiler waits vmcnt on use)
        *(f16x8*)(buf + ldsT)         = cvt8(rp[0], rp[1]);
        *(f16x8*)(buf + 8192 + ldsT)  = cvt8(rp[2], rp[3]);
        *(f16x8*)(buf + 16384 + ldsT) = cvt8(rp[4], rp[5]);
        __syncthreads();  // writes visible; prior-step MFMA reads drained
        if (s < 15) load(s + 1);  // lands during MFMA phase
        const char* PtB = buf;
        const char* QtB = buf + 16384;
        __builtin_amdgcn_s_setprio(1);
#pragma unroll
        for (int h = 0; h < 2; ++h) {
            const int ko = h ? off1 : off0;
            f16x8 qa[2], pb[2];
#pragma unroll
            for (int i = 0; i < 2; ++i)
                qa[i] = *(const f16x8*)(QtB + (wn + i * 16 + l15) * 128 + ko);
#pragma unroll
            for (int j = 0; j < 2; ++j)
                pb[j] = *(const f16x8*)(PtB + (wm + j * 16 + l15) * 128 + ko);
#pragma unroll
            for (int i = 0; i < 2; ++i)
#pragma unroll
                for (int j = 0; j < 2; ++j)
                    acc[i][j] = __builtin_amdgcn_mfma_f32_16x16x32_f16(qa[i], pb[j], acc[i][j], 0, 0, 0);
        }
        __builtin_amdgcn_s_setprio(0);
    }

    // epilogue: E = acc + be -> swz f16; emit |E| partials (slot nt*2+nh)
    const int slot = (n0 >> 6) * 2 + (wn >> 5);
#pragma unroll
    for (int j = 0; j < 2; ++j) {
        const int m = m0 + wm + j * 16 + l15;
        float rsum = 0.0f;
#pragma unroll
        for (int i = 0; i < 2; ++i) {
            const int n = n0 + wn + i * 16 + l4 * 4;
            const f32x4 bz = *(const f32x4*)(be + n);
            f16x4 hv;
#pragma unroll
            for (int e = 0; e < 4; ++e) {
                const float v = acc[i][j][e] + bz[e];
                rsum += fabsf(v);
                hv[e] = (half_t)v;
            }
            const int p = (n * 2) ^ ((m & 7) << 4);
            *(f16x4*)((char*)Eout + (size_t)m * ROWB + p) = hv;
        }
        rsum += __shfl_xor(rsum, 16, 64);
        rsum += __shfl_xor(rsum, 32, 64);
        if (l4 == 0) part0[(size_t)m * 32 + slot] = rsum;
    }
}

// ---- NT gemm (round-6 K-loop): tile 128m x 64n x 64k; 8 waves (4m x 2n),
// wave tile 32x32; triple-buffered LDS, counted vmcnt(3), setprio.
// EPI: 1 = mask(part_in)*0.5*tanh(.+bias) -> swz f16.
// EMIT: store per-row |out| partials to part_out (slot nt*2+nh).
template <bool EMIT>
__global__ __launch_bounds__(512)
void gemm8w(const half_t* __restrict__ P, const half_t* __restrict__ Q,
            const float* __restrict__ bias, const float* __restrict__ part_in,
            float* __restrict__ part_out, half_t* __restrict__ Out) {
    __shared__ alignas(16) char smem[3 * 24576];

    const int tid = threadIdx.x;
    const int bid = blockIdx.x;
    const int m0 = ((bid & 7) * 2 + ((bid >> 3) & 1)) * 128;
    const int n0 = (bid >> 4) * 64;

    const char* gP0 = (const char*)P + (size_t)(m0 + (tid >> 3)) * ROWB + (tid & 7) * 16;
    const char* gP1 = gP0 + (size_t)64 * ROWB;
    const char* gQ  = (const char*)Q + (size_t)(n0 + (tid >> 3)) * ROWB + (tid & 7) * 16;
    const int ldsT = tid * 16;

    const int lane = tid & 63;
    const int w = tid >> 6;
    const int wm = (w & 3) * 32;
    const int wn = (w >> 2) * 32;
    const int l15 = lane & 15, l4 = lane >> 4;
    const int off0 = (l4 * 16) ^ ((lane & 7) << 4);
    const int off1 = off0 ^ 64;

    f32x4 acc[2][2] = {};

    auto stage = [&](int s) {
        const int go = s * 128;
        char* base = smem + (s % 3) * 24576;
        gload16(gP0 + go, base + ldsT);
        gload16(gP1 + go, base + 8192 + ldsT);
        gload16(gQ + go, base + 16384 + ldsT);
    };

    stage(0);
    stage(1);

    for (int s = 0; s < 16; ++s) {
        if (s == 15) asm volatile("s_waitcnt vmcnt(0)" ::: "memory");
        else         asm volatile("s_waitcnt vmcnt(3)" ::: "memory");
        __builtin_amdgcn_s_barrier();
        asm volatile("" ::: "memory");
        if (s < 14) stage(s + 2);
        const char* PtB = smem + (s % 3) * 24576;
        const char* QtB = PtB + 16384;
        __builtin_amdgcn_s_setprio(1);
#pragma unroll
        for (int h = 0; h < 2; ++h) {
            const int ko = h ? off1 : off0;
            f16x8 qa[2], pb[2];
#pragma unroll
            for (int i = 0; i < 2; ++i)
                qa[i] = *(const f16x8*)(QtB + (wn + i * 16 + l15) * 128 + ko);
#pragma unroll
            for (int j = 0; j < 2; ++j)
                pb[j] = *(const f16x8*)(PtB + (wm + j * 16 + l15) * 128 + ko);
#pragma unroll
            for (int i = 0; i < 2; ++i)
#pragma unroll
                for (int j = 0; j < 2; ++j)
                    acc[i][j] = __builtin_amdgcn_mfma_f32_16x16x32_f16(qa[i], pb[j], acc[i][j], 0, 0, 0);
        }
        __builtin_amdgcn_s_setprio(0);
    }

    const int slot = (n0 >> 6) * 2 + (wn >> 5);
#pragma unroll
    for (int j = 0; j < 2; ++j) {
        const int m = m0 + wm + j * 16 + l15;
        const float msk = (part_sum(part_in, m) * (1.0f / 1024.0f) > EPS_GATE) ? 1.0f : 0.0f;
        float rsum = 0.0f;
#pragma unroll
        for (int i = 0; i < 2; ++i) {
            const int n = n0 + wn + i * 16 + l4 * 4;
            const f32x4 bz = *(const f32x4*)(bias + n);
            f16x4 hv;
#pragma unroll
            for (int e = 0; e < 4; ++e) {
                float v = msk * (0.5f * tanh_fast(acc[i][j][e] + bz[e]));
                if (EMIT) rsum += fabsf(v);
                hv[e] = (half_t)v;
            }
            const int p = (n * 2) ^ ((m & 7) << 4);
            *(f16x4*)((char*)Out + (size_t)m * ROWB + p) = hv;
        }
        if (EMIT) {
            rsum += __shfl_xor(rsum, 16, 64);
            rsum += __shfl_xor(rsum, 32, 64);
            if (l4 == 0) part_out[(size_t)m * 32 + slot] = rsum;
        }
    }
}

// ---- head gemm (round-11/13): tile 64m x 64n x 64k; 4 waves, 256 threads,
// 48 KB LDS, grid 256 (all CUs). out = H2 @ Wh^T + bh -> f32.
__global__ __launch_bounds__(256)
void gemm_head(const half_t* __restrict__ P, const half_t* __restrict__ Q,
               const float* __restrict__ bias, float* __restrict__ Out) {
    __shared__ alignas(16) char smem[3 * 16384];  // 48 KB

    const int tid = threadIdx.x;
    const int bid = blockIdx.x;
    const int m0 = ((bid & 7) * 4 + ((bid >> 3) & 3)) * 64;
    const int n0 = (bid >> 5) * 64;

    const char* gsP[2]; int ldP[2];
#pragma unroll
    for (int i = 0; i < 2; ++i) {
        const int G = tid + 256 * i;
        gsP[i] = (const char*)P + (size_t)(m0 + (G >> 3)) * ROWB + (G & 7) * 16;
        ldP[i] = G * 16;
    }
    const char* gsQ[2]; int ldQ[2];
#pragma unroll
    for (int c = 0; c < 2; ++c) {
        const int gg = tid + 256 * c;
        gsQ[c] = (const char*)Q + (size_t)(n0 + (gg >> 3)) * ROWB + (gg & 7) * 16;
        ldQ[c] = 8192 + gg * 16;
    }

    const int lane = tid & 63;
    const int w = tid >> 6;
    const int wm = (w & 1) * 32;
    const int wn = (w >> 1) * 32;
    const int l15 = lane & 15, l4 = lane >> 4;
    const int off0 = (l4 * 16) ^ ((lane & 7) << 4);
    const int off1 = off0 ^ 64;

    f32x4 acc[2][2] = {};

    auto stage = [&](int s) {
        const int go = s * 128;
        char* base = smem + (s % 3) * 16384;
#pragma unroll
        for (int i = 0; i < 2; ++i) gload16(gsP[i] + go, base + ldP[i]);
#pragma unroll
        for (int c = 0; c < 2; ++c) gload16(gsQ[c] + go, base + ldQ[c]);
    };

    stage(0);
    stage(1);

    for (int s = 0; s < 16; ++s) {
        if (s == 15) asm volatile("s_waitcnt vmcnt(0)" ::: "memory");
        else         asm volatile("s_waitcnt vmcnt(4)" ::: "memory");
        __builtin_amdgcn_s_barrier();
        asm volatile("" ::: "memory");
        if (s < 14) stage(s + 2);
        const char* PtB = smem + (s % 3) * 16384;
        const char* QtB = PtB + 8192;
        __builtin_amdgcn_s_setprio(1);
#pragma unroll
        for (int h = 0; h < 2; ++h) {
            const int ko = h ? off1 : off0;
            f16x8 qa[2], pb[2];
#pragma unroll
            for (int i = 0; i < 2; ++i)
                qa[i] = *(const f16x8*)(QtB + (wn + i * 16 + l15) * 128 + ko);
#pragma unroll
            for (int j = 0; j < 2; ++j)
                pb[j] = *(const f16x8*)(PtB + (wm + j * 16 + l15) * 128 + ko);
#pragma unroll
            for (int i = 0; i < 2; ++i)
#pragma unroll
                for (int j = 0; j < 2; ++j)
                    acc[i][j] = __builtin_amdgcn_mfma_f32_16x16x32_f16(qa[i], pb[j], acc[i][j], 0, 0, 0);
        }
        __builtin_amdgcn_s_setprio(0);
    }

#pragma unroll
    for (int j = 0; j < 2; ++j) {
        const int m = m0 + wm + j * 16 + l15;
#pragma unroll
        for (int i = 0; i < 2; ++i) {
            const int n = n0 + wn + i * 16 + l4 * 4;
            const f32x4 bz = *(const f32x4*)(bias + n);
            f32x4 o;
#pragma unroll
            for (int e = 0; e < 4; ++e) o[e] = acc[i][j][e] + bz[e];
            *(f32x4*)(Out + (size_t)m * 512 + n) = o;
        }
    }
}

extern "C" void kernel_launch(void* const* d_in, const int* in_sizes, int n_in,
                              void* d_out, int out_size, void* d_ws, size_t ws_size,
                              hipStream_t stream) {
    const float* x  = (const float*)d_in[0];  // [2048,1024]
    const float* We = (const float*)d_in[1];  // [1024,1024]
    const float* be = (const float*)d_in[2];  // [1024]
    const float* W  = (const float*)d_in[3];  // [3,1024,1024]
    const float* b  = (const float*)d_in[4];  // [3,1024]
    const float* Wh = (const float*)d_in[5];  // [512,1024]
    const float* bh = (const float*)d_in[6];  // [512]

    const int B = 2048, H = 1024, O = 512;

    half_t* s0    = (half_t*)d_ws;                   // H0 / H2
    half_t* s1    = s0 + (size_t)B * H;              // E / H1
    half_t* W16   = s1 + (size_t)B * H;              // 3M f16
    half_t* Wh16  = W16 + (size_t)3 * H * H;         // 0.5M f16
    float*  part0 = (float*)(Wh16 + (size_t)O * H);  // 2048 x 32 f32
    float*  part1 = part0 + 65536;
    float*  part2 = part1 + 65536;
    float*  out   = (float*)d_out;

    // E = x @ We^T + be (reg-staged fp32) + convert W/Wh + emit |E| partials
    gemmE_rs<<<368, 512, 0, stream>>>(x, We, be, W, Wh, W16, Wh16, part0, s1);
    // H0 = mask(part0) * 0.5*tanh(E @ W0^T + b0); emit part1
    gemm8w<true ><<<256, 512, 0, stream>>>(s1, W16, b, part0, part1, s0);
    // H1; emit part2
    gemm8w<true ><<<256, 512, 0, stream>>>(s0, W16 + (size_t)H * H, b + H,
                                           part1, part2, s1);
    // H2 (no emit)
    gemm8w<false><<<256, 512, 0, stream>>>(s1, W16 + (size_t)2 * H * H, b + 2 * H,
                                           part2, nullptr, s0);
    // head -> f32 out
    gemm_head<<<256, 256, 0, stream>>>(s0, Wh16, bh, out);
}

// Round 15
// 53.554 us; speedup vs baseline: 1.1739x; 1.1739x over previous
//
#include <hip/hip_runtime.h>
#include <math.h>

// LazyEqProp closed form (verified rounds 1-14):
//   E  = x @ We^T + be
//   m0 = mean|E|  > eps ;  H0 = m0 * 0.5*tanh(E  @ W0^T + b0)
//   m1 = mean|H0| > eps ;  H1 = m1 * 0.5*tanh(H0 @ W1^T + b1)
//   m2 = mean|H1| > eps ;  H2 = m2 * 0.5*tanh(H1 @ W2^T + b2)
//   out = H2 @ Wh^T + bh
//
// Round 15: REVERT to round 13 (best, 53.9us). Five structural variants
// (r9 convert-split, r10 BK=128, r11 2-block/CU, r12 k-split waves,
// r14 reg-staged gemm-E) all failed to beat it:
//  - gemms are LDS-read-BW-bound at the forced 128x64/8-wave tiling
//  - dispatch boundaries are the cheapest inter-layer fence on 8-XCD gfx950
//  - the convert pre-pass runs at HBM roofline and cannot be hidden
// Structure: convert_all + 4x gemm8w (128x64 tile, 8 waves, triple-buffered
// LDS, counted vmcnt(3), setprio, swizzled-f16 layout, global_load_lds w16,
// fused mask epilogue + atomicAdd row sums) + gemm2b head (64x64, grid 256).

using half_t = _Float16;
typedef _Float16 f16x4 __attribute__((ext_vector_type(4)));
typedef _Float16 f16x8 __attribute__((ext_vector_type(8)));
typedef float    f32x4 __attribute__((ext_vector_type(4)));

constexpr int KDIM = 1024;
constexpr int ROWB = KDIM * 2;  // bytes per swizzled f16 row
constexpr float EPS_GATE = 0.01f;

__device__ __forceinline__ float tanh_fast(float z) {
    return 1.0f - 2.0f / (__expf(2.0f * z) + 1.0f);  // safe at +-inf
}

__device__ __forceinline__ void gload16(const void* g, void* l) {
    __builtin_amdgcn_global_load_lds(
        (const __attribute__((address_space(1))) void*)g,
        (__attribute__((address_space(3))) void*)l, 16, 0, 0);
}

// ---- fp32 -> swizzled fp16 (row r, byte p holds element (p ^ ((r&7)<<4))/2)
//      + zero the 3 row-sum accumulators (blocks 0..5)
__global__ __launch_bounds__(256)
void convert_all(const float* __restrict__ x,  const float* __restrict__ We,
                 const float* __restrict__ W,  const float* __restrict__ Wh,
                 half_t* __restrict__ x16, half_t* __restrict__ We16,
                 half_t* __restrict__ W16, half_t* __restrict__ Wh16,
                 float* __restrict__ msum) {
    const int bid = blockIdx.x;
    const int t = threadIdx.x;
    if (bid < 6) ((f32x4*)msum)[bid * 256 + t] = f32x4{0.f, 0.f, 0.f, 0.f};
    const float* src; half_t* dst; int row;
    if (bid < 2048)      { src = x;  dst = x16;  row = bid; }
    else if (bid < 3072) { src = We; dst = We16; row = bid - 2048; }
    else if (bid < 6144) { src = W;  dst = W16;  row = bid - 3072; }
    else                 { src = Wh; dst = Wh16; row = bid - 6144; }
    const f32x4 v = *(const f32x4*)(src + (size_t)row * KDIM + 4 * t);
    f16x4 h;
    h[0] = (half_t)v[0]; h[1] = (half_t)v[1]; h[2] = (half_t)v[2]; h[3] = (half_t)v[3];
    const int p = (8 * t) ^ ((row & 7) << 4);
    *(f16x4*)((char*)dst + (size_t)row * ROWB + p) = h;
}

// ---- NT gemm (round-6): tile 128m x 64n x 64k; 8 waves (4m x 2n), wave tile
// 32x32; triple-buffered LDS (3 x 24 KB), counted vmcnt(3), setprio.
// EPI: 0 = bias -> swz f16; 1 = mask(msum_in)*0.5*tanh(.+bias) -> swz f16;
//      2 = bias -> f32.  EMIT: atomicAdd per-row |out| partials.
template <int EPI, bool EMIT>
__global__ __launch_bounds__(512)
void gemm8w(const half_t* __restrict__ P, const half_t* __restrict__ Q,
            const float* __restrict__ bias, const float* __restrict__ msum_in,
            float* __restrict__ msum_out, void* __restrict__ Out, int Nout) {
    __shared__ alignas(16) char smem[3 * 24576];

    const int tid = threadIdx.x;
    const int bid = blockIdx.x;
    // XCD-aware: xcd = bid&7 owns m-tiles {2x,2x+1} across all n-tiles.
    const int m0 = ((bid & 7) * 2 + ((bid >> 3) & 1)) * 128;
    const int n0 = (bid >> 4) * 64;

    const char* gP0 = (const char*)P + (size_t)(m0 + (tid >> 3)) * ROWB + (tid & 7) * 16;
    const char* gP1 = gP0 + (size_t)64 * ROWB;
    const char* gQ  = (const char*)Q + (size_t)(n0 + (tid >> 3)) * ROWB + (tid & 7) * 16;
    const int ldsT = tid * 16;

    const int lane = tid & 63;
    const int w = tid >> 6;
    const int wm = (w & 3) * 32;
    const int wn = (w >> 2) * 32;
    const int l15 = lane & 15, l4 = lane >> 4;
    const int off0 = (l4 * 16) ^ ((lane & 7) << 4);
    const int off1 = off0 ^ 64;

    f32x4 acc[2][2] = {};  // [n-frag][m-frag]

    auto stage = [&](int s) {
        const int go = s * 128;
        char* base = smem + (s % 3) * 24576;
        gload16(gP0 + go, base + ldsT);
        gload16(gP1 + go, base + 8192 + ldsT);
        gload16(gQ + go, base + 16384 + ldsT);
    };

    stage(0);
    stage(1);

    for (int s = 0; s < 16; ++s) {
        if (s == 15) asm volatile("s_waitcnt vmcnt(0)" ::: "memory");
        else         asm volatile("s_waitcnt vmcnt(3)" ::: "memory");
        __builtin_amdgcn_s_barrier();   // all waves' tile-s DMAs landed
        asm volatile("" ::: "memory");
        if (s < 14) stage(s + 2);       // overwrites buf((s-1)%3): reads done
        const char* PtB = smem + (s % 3) * 24576;
        const char* QtB = PtB + 16384;
        __builtin_amdgcn_s_setprio(1);
#pragma unroll
        for (int h = 0; h < 2; ++h) {
            const int ko = h ? off1 : off0;
            f16x8 qa[2], pb[2];
#pragma unroll
            for (int i = 0; i < 2; ++i)
                qa[i] = *(const f16x8*)(QtB + (wn + i * 16 + l15) * 128 + ko);
#pragma unroll
            for (int j = 0; j < 2; ++j)
                pb[j] = *(const f16x8*)(PtB + (wm + j * 16 + l15) * 128 + ko);
#pragma unroll
            for (int i = 0; i < 2; ++i)
#pragma unroll
                for (int j = 0; j < 2; ++j)
                    acc[i][j] = __builtin_amdgcn_mfma_f32_16x16x32_f16(qa[i], pb[j], acc[i][j], 0, 0, 0);
        }
        __builtin_amdgcn_s_setprio(0);
    }

    // ---- epilogue: lane holds m = m0+wm+j*16+l15, n = n0+wn+i*16+l4*4+e
#pragma unroll
    for (int j = 0; j < 2; ++j) {
        const int m = m0 + wm + j * 16 + l15;
        float msk = 1.0f;
        if (EPI == 1) msk = (msum_in[m] * (1.0f / 1024.0f) > EPS_GATE) ? 1.0f : 0.0f;
        float rsum = 0.0f;
#pragma unroll
        for (int i = 0; i < 2; ++i) {
            const int n = n0 + wn + i * 16 + l4 * 4;
            const f32x4 bz = *(const f32x4*)(bias + n);
            float v[4];
#pragma unroll
            for (int e = 0; e < 4; ++e) {
                v[e] = acc[i][j][e] + bz[e];
                if (EPI == 1) v[e] = msk * (0.5f * tanh_fast(v[e]));
                if (EMIT) rsum += fabsf(v[e]);
            }
            if (EPI == 2) {
                f32x4 o; o[0] = v[0]; o[1] = v[1]; o[2] = v[2]; o[3] = v[3];
                *(f32x4*)((float*)Out + (size_t)m * Nout + n) = o;
            } else {
                f16x4 hv;
                hv[0] = (half_t)v[0]; hv[1] = (half_t)v[1];
                hv[2] = (half_t)v[2]; hv[3] = (half_t)v[3];
                const int p = (n * 2) ^ ((m & 7) << 4);
                *(f16x4*)((char*)Out + (size_t)m * ROWB + p) = hv;
            }
        }
        if (EMIT) {  // reduce over the 4 l4-lanes sharing this row, one atomic
            rsum += __shfl_xor(rsum, 16, 64);
            rsum += __shfl_xor(rsum, 32, 64);
            if (l4 == 0) atomicAdd(msum_out + m, rsum);
        }
    }
}

// ---- NT gemm (round-11): tile 64m x 64n x 64k; 4 waves (2m x 2n), 256 thr,
// 48 KB LDS. Used for the HEAD only (grid 256 = all CUs, half per-block work).
template <int EPI, bool EMIT>
__global__ __launch_bounds__(256)
void gemm2b(const half_t* __restrict__ P, const half_t* __restrict__ Q,
            const float* __restrict__ bias, const float* __restrict__ msum_in,
            float* __restrict__ msum_out, void* __restrict__ Out, int Nout) {
    __shared__ alignas(16) char smem[3 * 16384];  // 48 KB

    const int tid = threadIdx.x;
    const int bid = blockIdx.x;
    // XCD-bijective: xcd = bid&7 owns m-panels {4x..4x+3}.
    const int m0 = ((bid & 7) * 4 + ((bid >> 3) & 3)) * 64;
    const int n0 = (bid >> 5) * 64;

    const char* gsP[2]; int ldP[2];
#pragma unroll
    for (int i = 0; i < 2; ++i) {
        const int G = tid + 256 * i;
        gsP[i] = (const char*)P + (size_t)(m0 + (G >> 3)) * ROWB + (G & 7) * 16;
        ldP[i] = G * 16;
    }
    const char* gsQ[2]; int ldQ[2];
#pragma unroll
    for (int c = 0; c < 2; ++c) {
        const int g = tid + 256 * c;
        gsQ[c] = (const char*)Q + (size_t)(n0 + (g >> 3)) * ROWB + (g & 7) * 16;
        ldQ[c] = 8192 + g * 16;
    }

    const int lane = tid & 63;
    const int w = tid >> 6;           // 4 waves: 2m x 2n, wave tile 32x32
    const int wm = (w & 1) * 32;
    const int wn = (w >> 1) * 32;
    const int l15 = lane & 15, l4 = lane >> 4;
    const int off0 = (l4 * 16) ^ ((lane & 7) << 4);
    const int off1 = off0 ^ 64;

    f32x4 acc[2][2] = {};

    auto stage = [&](int s) {
        const int go = s * 128;
        char* base = smem + (s % 3) * 16384;
#pragma unroll
        for (int i = 0; i < 2; ++i) gload16(gsP[i] + go, base + ldP[i]);
#pragma unroll
        for (int c = 0; c < 2; ++c) gload16(gsQ[c] + go, base + ldQ[c]);
    };

    stage(0);
    stage(1);

    for (int s = 0; s < 16; ++s) {
        if (s == 15) asm volatile("s_waitcnt vmcnt(0)" ::: "memory");
        else         asm volatile("s_waitcnt vmcnt(4)" ::: "memory");
        __builtin_amdgcn_s_barrier();
        asm volatile("" ::: "memory");
        if (s < 14) stage(s + 2);
        const char* PtB = smem + (s % 3) * 16384;
        const char* QtB = PtB + 8192;
        __builtin_amdgcn_s_setprio(1);
#pragma unroll
        for (int h = 0; h < 2; ++h) {
            const int ko = h ? off1 : off0;
            f16x8 qa[2], pb[2];
#pragma unroll
            for (int i = 0; i < 2; ++i)
                qa[i] = *(const f16x8*)(QtB + (wn + i * 16 + l15) * 128 + ko);
#pragma unroll
            for (int j = 0; j < 2; ++j)
                pb[j] = *(const f16x8*)(PtB + (wm + j * 16 + l15) * 128 + ko);
#pragma unroll
            for (int i = 0; i < 2; ++i)
#pragma unroll
                for (int j = 0; j < 2; ++j)
                    acc[i][j] = __builtin_amdgcn_mfma_f32_16x16x32_f16(qa[i], pb[j], acc[i][j], 0, 0, 0);
        }
        __builtin_amdgcn_s_setprio(0);
    }

#pragma unroll
    for (int j = 0; j < 2; ++j) {
        const int m = m0 + wm + j * 16 + l15;
        float msk = 1.0f;
        if (EPI == 1) msk = (msum_in[m] * (1.0f / 1024.0f) > EPS_GATE) ? 1.0f : 0.0f;
        float rsum = 0.0f;
#pragma unroll
        for (int i = 0; i < 2; ++i) {
            const int n = n0 + wn + i * 16 + l4 * 4;
            const f32x4 bz = *(const f32x4*)(bias + n);
            float v[4];
#pragma unroll
            for (int e = 0; e < 4; ++e) {
                v[e] = acc[i][j][e] + bz[e];
                if (EPI == 1) v[e] = msk * (0.5f * tanh_fast(v[e]));
                if (EMIT) rsum += fabsf(v[e]);
            }
            if (EPI == 2) {
                f32x4 o; o[0] = v[0]; o[1] = v[1]; o[2] = v[2]; o[3] = v[3];
                *(f32x4*)((float*)Out + (size_t)m * Nout + n) = o;
            } else {
                f16x4 hv;
                hv[0] = (half_t)v[0]; hv[1] = (half_t)v[1];
                hv[2] = (half_t)v[2]; hv[3] = (half_t)v[3];
                const int p = (n * 2) ^ ((m & 7) << 4);
                *(f16x4*)((char*)Out + (size_t)m * ROWB + p) = hv;
            }
        }
        if (EMIT) {
            rsum += __shfl_xor(rsum, 16, 64);
            rsum += __shfl_xor(rsum, 32, 64);
            if (l4 == 0) atomicAdd(msum_out + m, rsum);
        }
    }
}

extern "C" void kernel_launch(void* const* d_in, const int* in_sizes, int n_in,
                              void* d_out, int out_size, void* d_ws, size_t ws_size,
                              hipStream_t stream) {
    const float* x  = (const float*)d_in[0];  // [2048,1024]
    const float* We = (const float*)d_in[1];  // [1024,1024]
    const float* be = (const float*)d_in[2];  // [1024]
    const float* W  = (const float*)d_in[3];  // [3,1024,1024]
    const float* b  = (const float*)d_in[4];  // [3,1024]
    const float* Wh = (const float*)d_in[5];  // [512,1024]
    const float* bh = (const float*)d_in[6];  // [512]

    const int B = 2048, H = 1024, O = 512;

    half_t* s0   = (half_t*)d_ws;                   // x16 / H0 / H2
    half_t* s1   = s0 + (size_t)B * H;              // E / H1
    half_t* We16 = s1 + (size_t)B * H;
    half_t* W16  = We16 + (size_t)H * H;
    half_t* Wh16 = W16 + (size_t)3 * H * H;
    float*  msum = (float*)(Wh16 + (size_t)O * H);  // 3 x 2048 f32
    float*  out  = (float*)d_out;

    convert_all<<<6656, 256, 0, stream>>>(x, We, W, Wh, s0, We16, W16, Wh16, msum);

    // E = x @ We^T + be; emit |E| row sums -> msum0
    gemm8w<0, true ><<<256, 512, 0, stream>>>(s0, We16, be, nullptr, msum, s1, H);
    // H0 = m0 * 0.5*tanh(E @ W0^T + b0); emit -> msum1
    gemm8w<1, true ><<<256, 512, 0, stream>>>(s1, W16, b, msum, msum + 2048, s0, H);
    // H1; emit -> msum2
    gemm8w<1, true ><<<256, 512, 0, stream>>>(s0, W16 + (size_t)H * H, b + H,
                                              msum + 2048, msum + 4096, s1, H);
    // H2 (no emit)
    gemm8w<1, false><<<256, 512, 0, stream>>>(s1, W16 + (size_t)2 * H * H, b + 2 * H,
                                              msum + 4096, nullptr, s0, H);
    // head -> f32 out: 64x64 tiles, 256 blocks (all CUs)
    gemm2b<2, false><<<256, 256, 0, stream>>>(s0, Wh16, bh, nullptr, nullptr, out, O);
}